// Round 4
// baseline (3498.715 us; speedup 1.0000x reference)
//
#include <hip/hip_runtime.h>

#define T_STEPS 512
#define B_ROWS  64
#define F_DIM   256
#define U_DIM   1024
#define G3      3072   // 3*U
#define KTOT    1280   // F + U
#define LDSK    1292   // KTOT + 12 bf16 pad (bank shift 6/row; measured 0 conflicts)
#define LDS_BYTES (48 * LDSK * 2 + 512)

typedef __bf16 bf16x8 __attribute__((ext_vector_type(8)));
typedef float  f32x4  __attribute__((ext_vector_type(4)));
typedef unsigned int u32x2 __attribute__((ext_vector_type(2)));

__device__ __forceinline__ float sigmoidf_(float v) {
    return 1.f / (1.f + __expf(-v));
}
__device__ __forceinline__ float tanhf_(float v) {
    float e2 = __expf(2.f * v);
    return 1.f - 2.f / (e2 + 1.f);
}

// ---------------------------------------------------------------------------
// Transpose + cvt: src [Kdim][3072] f32  ->  dst [3072][Kdim] bf16
// ---------------------------------------------------------------------------
__global__ __launch_bounds__(256) void transpose_cvt_kernel(
    const float* __restrict__ src, __bf16* __restrict__ dst, int Kdim)
{
    __shared__ float tile[32][33];
    const int n0 = blockIdx.x * 32;
    const int k0 = blockIdx.y * 32;
    const int j  = threadIdx.x & 31;
    const int i0 = threadIdx.x >> 5;   // 0..7
#pragma unroll
    for (int s = 0; s < 4; ++s) {
        int i = i0 * 4 + s;
        tile[i][j] = src[(size_t)(k0 + i) * G3 + n0 + j];
    }
    __syncthreads();
#pragma unroll
    for (int s = 0; s < 4; ++s) {
        int i = i0 * 4 + s;
        dst[(size_t)(n0 + i) * Kdim + k0 + j] = (__bf16)tile[j][i];
    }
}

// ---------------------------------------------------------------------------
// Init: hidden f32 -> bf16 hbufA in TILED layout [rt][c][row16][u16];
// reset flags. Grid 256 x 256.
// ---------------------------------------------------------------------------
__global__ __launch_bounds__(256) void init_kernel(
    const float* __restrict__ hidden, __bf16* __restrict__ hbufA,
    unsigned int* __restrict__ flags)
{
    const int i = blockIdx.x * 256 + threadIdx.x;   // 0..65535
    const int row = i >> 10, u = i & 1023;
    const int rt = row >> 4, rl = row & 15, c = u >> 4, ul = u & 15;
    hbufA[((rt * 64 + c) << 8) + (rl << 4) + ul] = (__bf16)hidden[i];
    if (blockIdx.x == 0) flags[threadIdx.x] = 0u;
}

// ---------------------------------------------------------------------------
// Persistent GRU. Grid = 256 blocks x 64 threads (1 wave, 1 block/CU).
// Block bid: coltile c = bid & 63 (16 u's), rowtile rt = bid >> 6 (16 rows).
// Weights (3 gates x 16 u x 1280 k, bf16) live in LDS for all 512 steps.
// h exchange: tiled bf16 buffers in MALL (sc0 sc1), one coalesced 512B
// store per block per step; per-block monotonic flags; no grid barrier.
// A-frag: lane holds A[row=l&15][k=(l>>4)*8+e];  B-frag: B[k][col=l&15];
// C/D: col=l&15, row=(l>>4)*4+j.  f32 carry stays in registers.
// ---------------------------------------------------------------------------
__global__ __launch_bounds__(64, 1) void gru_persistent(
    const float* __restrict__ x,       // [64][512][256] f32
    const float* __restrict__ hidden,  // [64][1024] f32
    const float* __restrict__ bias,    // [2][3072] f32
    const __bf16* __restrict__ Kt,     // [3072][256]
    const __bf16* __restrict__ Rt,     // [3072][1024]
    __bf16* __restrict__ hbufA,        // [4][64][256] bf16 tiled
    __bf16* __restrict__ hbufB,        // [4][64][256] bf16 tiled
    unsigned int* __restrict__ flags,  // [256]
    float* __restrict__ out)           // [64][512][1024] f32 (+ state tail)
{
    extern __shared__ __bf16 wlds[];   // [48][LDSK] weights + 512B pack tile
    __bf16* hpack = wlds + 48 * LDSK;  // [16][16] bf16
    const int lane = threadIdx.x & 63;
    const int rc   = lane & 15;
    const int kg   = lane >> 4;
    const int bid  = blockIdx.x;
    const int c    = bid & 63;
    const int rt   = bid >> 6;
    const int u    = (c << 4) + rc;
    const int row0 = rt << 4;

    // ---- stage weight slice into LDS (once) ----
    for (int i = lane; i < 48 * 160; i += 64) {
        const int rrow = i / 160;
        const int ch   = i - rrow * 160;          // 16B chunk index
        const int g    = rrow >> 4;
        const int ul   = rrow & 15;
        const int gu   = g * U_DIM + (c << 4) + ul;
        bf16x8 v;
        if (ch < 32) v = *(const bf16x8*)(Kt + (size_t)gu * F_DIM + ch * 8);
        else         v = *(const bf16x8*)(Rt + (size_t)gu * U_DIM + (ch - 32) * 8);
        *(bf16x8*)(wlds + rrow * LDSK + ch * 8) = v;
    }
    __syncthreads();

    // ---- per-thread invariants ----
    float hprev[4];
#pragma unroll
    for (int j = 0; j < 4; ++j)
        hprev[j] = hidden[(size_t)(row0 + (kg << 2) + j) * U_DIM + u];

    const float bz_ = bias[u]             + bias[G3 + u];
    const float br_ = bias[U_DIM + u]     + bias[G3 + U_DIM + u];
    const float bhx = bias[2 * U_DIM + u];
    const float bhr = bias[G3 + 2 * U_DIM + u];

    const __bf16* pz = wlds + (0 * 16 + rc) * LDSK + (kg << 3);
    const __bf16* pr = wlds + (1 * 16 + rc) * LDSK + (kg << 3);
    const __bf16* ph = wlds + (2 * 16 + rc) * LDSK + (kg << 3);

    const float* xbase = x + (size_t)(row0 + rc) * (T_STEPS * F_DIM) + (kg << 3);
    const unsigned int* fp = flags + (rt << 6) + lane;  // my group's 64 flags

    // consumer h read base (tiled layout), lane-dependent part
    const int grpoff = (rt << 6) << 8;                       // rt*64*256 elems
    const int lanoff = ((kg >> 1) << 8) + (rc << 4) + ((kg & 1) << 3);
    // producer tile base (elements)
    const int myoff  = ((rt * 64 + c) << 8) + ((lane >> 2) << 4) + ((lane & 3) << 2);

    for (int t = 0; t < T_STEPS; ++t) {
        f32x4 accZ  = {0.f, 0.f, 0.f, 0.f};
        f32x4 accR  = {0.f, 0.f, 0.f, 0.f};
        f32x4 accHX = {0.f, 0.f, 0.f, 0.f};
        f32x4 accHR = {0.f, 0.f, 0.f, 0.f};

        // ---- X phase (independent of h; runs before the flag wait) ----
        const float* ap = xbase + t * F_DIM;
#pragma unroll
        for (int k0 = 0; k0 < F_DIM; k0 += 32) {
            const float4 a0 = *(const float4*)(ap + k0);
            const float4 a1 = *(const float4*)(ap + k0 + 4);
            bf16x8 af;
            af[0] = (__bf16)a0.x; af[1] = (__bf16)a0.y;
            af[2] = (__bf16)a0.z; af[3] = (__bf16)a0.w;
            af[4] = (__bf16)a1.x; af[5] = (__bf16)a1.y;
            af[6] = (__bf16)a1.z; af[7] = (__bf16)a1.w;
            accZ  = __builtin_amdgcn_mfma_f32_16x16x32_bf16(af, *(const bf16x8*)(pz + k0), accZ,  0, 0, 0);
            accR  = __builtin_amdgcn_mfma_f32_16x16x32_bf16(af, *(const bf16x8*)(pr + k0), accR,  0, 0, 0);
            accHX = __builtin_amdgcn_mfma_f32_16x16x32_bf16(af, *(const bf16x8*)(ph + k0), accHX, 0, 0, 0);
        }

        // ---- group barrier: wait for all 64 siblings to have stored h(t-1) ----
        if (t > 0) {
            const unsigned int target = (unsigned int)t;
            for (;;) {
                unsigned int f;
                asm volatile("global_load_dword %0, %1, off sc0 sc1\n\t"
                             "s_waitcnt vmcnt(0)"
                             : "=v"(f) : "v"(fp) : "memory");
                if (__all((int)(f >= target))) break;
            }
        }

        // ---- load h(t-1) A-fragments straight to registers (MALL bypass) ----
        const __bf16* hread = (t & 1) ? hbufB : hbufA;
        const __bf16* hb = hread + grpoff + lanoff;
        bf16x8 hfrag[32];
#define HL(q, kil, lit)                                                        \
        asm volatile("global_load_dwordx4 %0, %1, off offset:" lit " sc0 sc1"  \
                     : "=v"(hfrag[(q)*4 + (kil)]) : "v"(hb + (q)*2048) : "memory");
        HL(0,0,"0") HL(0,1,"1024") HL(0,2,"2048") HL(0,3,"3072")
        HL(1,0,"0") HL(1,1,"1024") HL(1,2,"2048") HL(1,3,"3072")
        HL(2,0,"0") HL(2,1,"1024") HL(2,2,"2048") HL(2,3,"3072")
        HL(3,0,"0") HL(3,1,"1024") HL(3,2,"2048") HL(3,3,"3072")
        HL(4,0,"0") HL(4,1,"1024") HL(4,2,"2048") HL(4,3,"3072")
        HL(5,0,"0") HL(5,1,"1024") HL(5,2,"2048") HL(5,3,"3072")
        HL(6,0,"0") HL(6,1,"1024") HL(6,2,"2048") HL(6,3,"3072")
        HL(7,0,"0") HL(7,1,"1024") HL(7,2,"2048") HL(7,3,"3072")
#undef HL

        // ---- H phase: first half overlapped with remaining load latency ----
        asm volatile("s_waitcnt vmcnt(16)" ::: "memory");
        __builtin_amdgcn_sched_barrier(0);
#pragma unroll
        for (int ki = 0; ki < 16; ++ki) {
            const bf16x8 af = hfrag[ki];
            accZ  = __builtin_amdgcn_mfma_f32_16x16x32_bf16(af, *(const bf16x8*)(pz + F_DIM + ki * 32), accZ,  0, 0, 0);
            accR  = __builtin_amdgcn_mfma_f32_16x16x32_bf16(af, *(const bf16x8*)(pr + F_DIM + ki * 32), accR,  0, 0, 0);
            accHR = __builtin_amdgcn_mfma_f32_16x16x32_bf16(af, *(const bf16x8*)(ph + F_DIM + ki * 32), accHR, 0, 0, 0);
        }
        asm volatile("s_waitcnt vmcnt(0)" ::: "memory");
        __builtin_amdgcn_sched_barrier(0);
#pragma unroll
        for (int ki = 16; ki < 32; ++ki) {
            const bf16x8 af = hfrag[ki];
            accZ  = __builtin_amdgcn_mfma_f32_16x16x32_bf16(af, *(const bf16x8*)(pz + F_DIM + ki * 32), accZ,  0, 0, 0);
            accR  = __builtin_amdgcn_mfma_f32_16x16x32_bf16(af, *(const bf16x8*)(pr + F_DIM + ki * 32), accR,  0, 0, 0);
            accHR = __builtin_amdgcn_mfma_f32_16x16x32_bf16(af, *(const bf16x8*)(ph + F_DIM + ki * 32), accHR, 0, 0, 0);
        }

        // ---- gates in f32, register carry ----
        float hn[4];
#pragma unroll
        for (int j = 0; j < 4; ++j) {
            const float z  = sigmoidf_(accZ[j] + bz_);
            const float r  = sigmoidf_(accR[j] + br_);
            const float hh = tanhf_(accHX[j] + bhx + r * (accHR[j] + bhr));
            hn[j] = z * hprev[j] + (1.f - z) * hh;
            hprev[j] = hn[j];
        }

        // ---- pack h tile via LDS (single wave: no barrier needed) ----
        __bf16* hwrite = (t & 1) ? hbufA : hbufB;
#pragma unroll
        for (int j = 0; j < 4; ++j)
            hpack[(((kg << 2) + j) << 4) + rc] = (__bf16)hn[j];
        // lane reads row = lane>>2, u4 = (lane&3)*4 : contiguous 8B
        const u32x2 hv = *(const u32x2*)(hpack + ((lane >> 2) << 4) + ((lane & 3) << 2));
        asm volatile("global_store_dwordx2 %0, %1, off sc0 sc1"
                     :: "v"(hwrite + myoff), "v"(hv) : "memory");
        asm volatile("s_waitcnt vmcnt(0)" ::: "memory");
        if (lane == 0) {
            const unsigned int tv = (unsigned int)(t + 1);
            asm volatile("global_store_dword %0, %1, off sc0 sc1"
                         :: "v"(flags + bid), "v"(tv) : "memory");
        }

        // ---- out stores AFTER the publish (off the critical path) ----
#pragma unroll
        for (int j = 0; j < 4; ++j) {
            const int row = row0 + (kg << 2) + j;
            out[((size_t)row * T_STEPS + t) * U_DIM + u] = hn[j];
            if (t == T_STEPS - 1)
                out[(size_t)B_ROWS * T_STEPS * U_DIM + (size_t)row * U_DIM + u] = hn[j];
        }
    }
}

extern "C" void kernel_launch(void* const* d_in, const int* in_sizes, int n_in,
                              void* d_out, int out_size, void* d_ws, size_t ws_size,
                              hipStream_t stream)
{
    const float* x      = (const float*)d_in[0];  // [64,512,256]
    const float* hidden = (const float*)d_in[1];  // [64,1024]
    const float* kernel = (const float*)d_in[2];  // [256,3072]
    const float* rker   = (const float*)d_in[3];  // [1024,3072]
    const float* bias   = (const float*)d_in[4];  // [2,3072]
    float* out = (float*)d_out;

    const size_t kt_el = (size_t)G3 * F_DIM;
    const size_t rt_el = (size_t)G3 * U_DIM;
    const size_t h_el  = (size_t)B_ROWS * U_DIM;
    __bf16* Kt = (__bf16*)d_ws;
    __bf16* Rt = Kt + kt_el;
    __bf16* hA = Rt + rt_el;
    __bf16* hB = hA + h_el;
    unsigned int* flags = (unsigned int*)(hB + h_el);

    hipLaunchKernelGGL(transpose_cvt_kernel, dim3(G3 / 32, F_DIM / 32), dim3(256),
                       0, stream, kernel, Kt, F_DIM);
    hipLaunchKernelGGL(transpose_cvt_kernel, dim3(G3 / 32, U_DIM / 32), dim3(256),
                       0, stream, rker, Rt, U_DIM);
    hipLaunchKernelGGL(init_kernel, dim3(256), dim3(256), 0, stream,
                       hidden, hA, flags);

    void* kx = (void*)&x;  void* kh = (void*)&hidden; void* kb = (void*)&bias;
    void* kK = (void*)&Kt; void* kR = (void*)&Rt;
    void* kA = (void*)&hA; void* kB2 = (void*)&hB;
    void* kF = (void*)&flags; void* ko = (void*)&out;
    void* args[9] = { kx, kh, kb, kK, kR, kA, kB2, kF, ko };

    auto kfn = gru_persistent;
    hipFuncSetAttribute((const void*)kfn,
                        hipFuncAttributeMaxDynamicSharedMemorySize, LDS_BYTES);
    hipLaunchCooperativeKernel(kfn, dim3(256), dim3(64), args, LDS_BYTES, stream);
}